// Round 1
// baseline (185.737 us; speedup 1.0000x reference)
//
#include <hip/hip_runtime.h>
#include <hip/hip_bf16.h>
#include <stdint.h>

#define B_ 64
#define S_ 512
#define I_ 256
#define H_ 1024
#define O_ 128
#define M_ (B_*S_)   // 32768

typedef __bf16 bf16x8 __attribute__((ext_vector_type(8)));
typedef float f32x4 __attribute__((ext_vector_type(4)));

__device__ __forceinline__ unsigned short f2bf(float f) {
    unsigned u = __float_as_uint(f);
    unsigned rounding = 0x7FFFu + ((u >> 16) & 1u);
    u += rounding;
    return (unsigned short)(u >> 16);
}

// ---------------- K0: fp32 -> bf16 convert + firstCross init ----------------
__global__ void __launch_bounds__(256) k0_convert(
    const float* __restrict__ x, const float* __restrict__ Win,
    unsigned short* __restrict__ xbf, unsigned short* __restrict__ wbf,
    unsigned* __restrict__ firstCross)
{
    const size_t NX = (size_t)M_ * I_;   // 8388608
    const size_t NW = (size_t)H_ * I_;   // 262144
    size_t tid = (size_t)blockIdx.x * 256 + threadIdx.x;
    size_t base = tid * 4;
    if (base < NX) {
        float4 v = *(const float4*)(x + base);
        ushort4 o;
        o.x = f2bf(v.x); o.y = f2bf(v.y); o.z = f2bf(v.z); o.w = f2bf(v.w);
        *(ushort4*)(xbf + base) = o;
    } else if (base < NX + NW) {
        size_t b2 = base - NX;
        float4 v = *(const float4*)(Win + b2);
        ushort4 o;
        o.x = f2bf(v.x); o.y = f2bf(v.y); o.z = f2bf(v.z); o.w = f2bf(v.w);
        *(ushort4*)(wbf + b2) = o;
    }
    if (blockIdx.x == 0 && threadIdx.x < 64) firstCross[threadIdx.x] = 0xFFFFFFFFu;
}

// ---------------- K1: ff = x @ W_in^T + b_in  (bf16 MFMA, fp32 out) ---------
// 128x128 tile, BK=32, 256 threads (4 waves, each 64x64 quadrant = 4x4 MFMAs)
__global__ void __launch_bounds__(256) k1_gemm(
    const unsigned short* __restrict__ xbf,   // [M_][I_]
    const unsigned short* __restrict__ wbf,   // [H_][I_]
    const float* __restrict__ b_in,           // [H_]
    float* __restrict__ ff)                   // [M_][H_]
{
    __shared__ unsigned short lA[128 * 32];
    __shared__ unsigned short lB[128 * 32];

    const int tid  = threadIdx.x;
    const int w    = tid >> 6;
    const int lane = tid & 63;
    const int bn   = blockIdx.x & 7;
    const int bm   = blockIdx.x >> 3;
    const int wave_m = (w >> 1) * 64;
    const int wave_n = (w & 1) * 64;
    const int colrow = lane & 15;
    const int quad   = lane >> 4;

    f32x4 acc[4][4];
#pragma unroll
    for (int mi = 0; mi < 4; ++mi)
#pragma unroll
        for (int ni = 0; ni < 4; ++ni)
            acc[mi][ni] = (f32x4){0.f, 0.f, 0.f, 0.f};

    // staging: each wave stages 2KB of A and 2KB of B per BK-tile (2 instrs each)
    const int rstage = lane >> 2;          // 0..15 (row within 16-row group)
    const int kcol   = (lane & 3) * 8;     // shorts within the 32-elem k row
    const unsigned short* gA0 = xbf + ((size_t)(bm * 128 + w * 32 + rstage)) * I_ + kcol;
    const unsigned short* gB0 = wbf + ((size_t)(bn * 128 + w * 32 + rstage)) * I_ + kcol;
    unsigned short* lA_w = lA + w * 1024;
    unsigned short* lB_w = lB + w * 1024;

    for (int kt = 0; kt < 8; ++kt) {
        const int k0 = kt * 32;
        __syncthreads();
#pragma unroll
        for (int j = 0; j < 2; ++j) {
            __builtin_amdgcn_global_load_lds(
                (const __attribute__((address_space(1))) void*)(gA0 + (size_t)j * 16 * I_ + k0),
                (__attribute__((address_space(3))) void*)(lA_w + j * 512), 16, 0, 0);
            __builtin_amdgcn_global_load_lds(
                (const __attribute__((address_space(1))) void*)(gB0 + (size_t)j * 16 * I_ + k0),
                (__attribute__((address_space(3))) void*)(lB_w + j * 512), 16, 0, 0);
        }
        __syncthreads();

        bf16x8 af[4], bfr[4];
#pragma unroll
        for (int i = 0; i < 4; ++i) {
            af[i]  = *(const bf16x8*)&lA[(wave_m + i * 16 + colrow) * 32 + quad * 8];
            bfr[i] = *(const bf16x8*)&lB[(wave_n + i * 16 + colrow) * 32 + quad * 8];
        }
#pragma unroll
        for (int mi = 0; mi < 4; ++mi)
#pragma unroll
            for (int ni = 0; ni < 4; ++ni)
                acc[mi][ni] = __builtin_amdgcn_mfma_f32_16x16x32_bf16(
                    af[mi], bfr[ni], acc[mi][ni], 0, 0, 0);
    }

    // epilogue: D[m = quad*4 + reg][n = lane&15], add b_in, store fp32
    const size_t mrow0 = (size_t)bm * 128 + wave_m + quad * 4;
    const int ncol0 = bn * 128 + wave_n + colrow;
#pragma unroll
    for (int ni = 0; ni < 4; ++ni) {
        const int n = ncol0 + ni * 16;
        const float bias = b_in[n];
#pragma unroll
        for (int mi = 0; mi < 4; ++mi) {
#pragma unroll
            for (int r = 0; r < 4; ++r) {
                ff[(mrow0 + mi * 16 + r) * H_ + n] = acc[mi][ni][r] + bias;
            }
        }
    }
}

// ---------------- K2: speculative no-spike scan, detect first crossing ------
__global__ void __launch_bounds__(256) k2_scan(
    const float* __restrict__ ff, const float* __restrict__ b_rec,
    const float* __restrict__ tau_m, const float* __restrict__ tau_n,
    unsigned* __restrict__ firstCross)
{
    const int b = blockIdx.x >> 2;
    const int h = ((blockIdx.x & 3) << 8) | threadIdx.x;
    const float alpha = 1.f / (1.f + expf(-tau_m[h]));
    const float beta  = 1.f / (1.f + expf(-tau_n[h]));
    const float br = b_rec[h];
    const float* f = ff + (size_t)b * S_ * H_ + h;
    float d = 0.f, mem = 0.f;
    unsigned cross = 0xFFFFFFFFu;
    for (int t0 = 0; t0 < S_; t0 += 8) {
        float v[8];
#pragma unroll
        for (int u = 0; u < 8; ++u) v[u] = f[(size_t)(t0 + u) * H_];
#pragma unroll
        for (int u = 0; u < 8; ++u) {
            float tot = v[u] + br;
            d = beta * d + (1.f - beta) * tot;
            mem = alpha * mem + (1.f - alpha) * d;
            if (mem > 1.0f && cross == 0xFFFFFFFFu) cross = (unsigned)(t0 + u);
        }
    }
    if (cross != 0xFFFFFFFFu) atomicMin(firstCross + b, cross);
}

// ---------------- K3: exact sequential repair (runs ~never) -----------------
__global__ void __launch_bounds__(1024) k3_repair(
    const float* __restrict__ ff, const float* __restrict__ W_rec,
    const float* __restrict__ b_rec,
    const float* __restrict__ tau_m, const float* __restrict__ tau_n,
    const unsigned* __restrict__ firstCross,
    unsigned long long* __restrict__ gmask)
{
    const int b = blockIdx.x;
    if (firstCross[b] == 0xFFFFFFFFu) return;
    const int h = threadIdx.x;
    __shared__ unsigned long long msk[16];
    if (h < 16) msk[h] = 0ull;
    __syncthreads();
    const float alpha = 1.f / (1.f + expf(-tau_m[h]));
    const float beta  = 1.f / (1.f + expf(-tau_n[h]));
    const float br = b_rec[h];
    const float* f = ff + (size_t)b * S_ * H_ + h;
    const float* wr = W_rec + (size_t)h * H_;
    float d = 0.f, mem = 0.f;
    for (int t = 0; t < S_; ++t) {
        float rec = 0.f;
#pragma unroll
        for (int w = 0; w < 16; ++w) {
            unsigned long long mw = msk[w];
            while (mw) {
                int bit = __ffsll((long long)mw) - 1;
                rec += wr[(w << 6) + bit];
                mw &= (mw - 1);
            }
        }
        float tot = (f[(size_t)t * H_] + br) + rec;
        d = beta * d + (1.f - beta) * tot;
        mem = alpha * mem + (1.f - alpha) * d;
        int sp = (mem > 1.0f) ? 1 : 0;
        if (sp) mem = 0.f;
        unsigned long long bal = __ballot(sp);
        __syncthreads();
        if ((h & 63) == 0) msk[h >> 6] = bal;
        __syncthreads();
        if ((h & 63) == 0) gmask[((size_t)b * S_ + t) * 16 + (h >> 6)] = bal;
    }
}

// ---------------- K4: out = sigmoid(spike @ W_out^T + b_out) ----------------
__global__ void __launch_bounds__(256) k4_out(
    const float* __restrict__ W_out, const float* __restrict__ b_out,
    const unsigned* __restrict__ firstCross,
    const unsigned long long* __restrict__ gmask,
    float* __restrict__ out)
{
    const int idx = blockIdx.x * 256 + threadIdx.x;
    const int o  = idx & (O_ - 1);
    const int bt = idx >> 7;          // b*S_ + t
    const int b  = bt >> 9;
    const int t  = bt & (S_ - 1);
    float logit = b_out[o];
    if ((unsigned)t >= firstCross[b]) {
        const unsigned long long* m = gmask + (size_t)bt * 16;
        const float* wo = W_out + (size_t)o * H_;
#pragma unroll 4
        for (int w = 0; w < 16; ++w) {
            unsigned long long mw = m[w];
            while (mw) {
                int bit = __ffsll((long long)mw) - 1;
                logit += wo[(w << 6) + bit];
                mw &= (mw - 1);
            }
        }
    }
    out[idx] = 1.f / (1.f + expf(-logit));
}

extern "C" void kernel_launch(void* const* d_in, const int* in_sizes, int n_in,
                              void* d_out, int out_size, void* d_ws, size_t ws_size,
                              hipStream_t stream) {
    const float* x     = (const float*)d_in[0];
    const float* W_in  = (const float*)d_in[1];
    const float* b_in  = (const float*)d_in[2];
    const float* W_rec = (const float*)d_in[3];
    const float* b_rec = (const float*)d_in[4];
    const float* tau_m = (const float*)d_in[5];
    const float* tau_n = (const float*)d_in[6];
    const float* W_out = (const float*)d_in[7];
    const float* b_out = (const float*)d_in[8];
    float* out = (float*)d_out;

    char* ws = (char*)d_ws;
    size_t off = 0;
    float* ff = (float*)(ws + off);                 off += (size_t)M_ * H_ * 4;      // 128 MB
    unsigned short* xbf = (unsigned short*)(ws + off); off += (size_t)M_ * I_ * 2;   // 16 MB
    unsigned short* wbf = (unsigned short*)(ws + off); off += (size_t)H_ * I_ * 2;   // 0.5 MB
    unsigned long long* gmask = (unsigned long long*)(ws + off); off += (size_t)B_ * S_ * 16 * 8; // 4 MB
    unsigned* firstCross = (unsigned*)(ws + off);   off += 256;
    if (ws_size < off) return;  // workspace too small: fail visibly

    k0_convert<<<8448, 256, 0, stream>>>(x, W_in, xbf, wbf, firstCross);
    k1_gemm<<<2048, 256, 0, stream>>>(xbf, wbf, b_in, ff);
    k2_scan<<<256, 256, 0, stream>>>(ff, b_rec, tau_m, tau_n, firstCross);
    k3_repair<<<64, 1024, 0, stream>>>(ff, W_rec, b_rec, tau_m, tau_n, firstCross, gmask);
    k4_out<<<16384, 256, 0, stream>>>(W_out, b_out, firstCross, gmask, out);
}

// Round 2
// 144.380 us; speedup vs baseline: 1.2865x; 1.2865x over previous
//
#include <hip/hip_runtime.h>
#include <hip/hip_bf16.h>
#include <stdint.h>

#define B_ 64
#define S_ 512
#define I_ 256
#define H_ 1024
#define O_ 128
#define M_ (B_*S_)   // 32768
#define LST 136      // lS t-stride (bf16 elems): 16B-aligned rows, even bank spread

typedef __bf16 bf16x8 __attribute__((ext_vector_type(8)));
typedef unsigned short u16x4 __attribute__((ext_vector_type(4)));
typedef unsigned short u16x8 __attribute__((ext_vector_type(8)));
typedef float f32x4 __attribute__((ext_vector_type(4)));

__device__ __forceinline__ unsigned short f2bf(float f) {
    unsigned u = __float_as_uint(f);
    u += 0x7FFFu + ((u >> 16) & 1u);
    return (unsigned short)(u >> 16);
}
__device__ __forceinline__ float bf2f(unsigned short s) {
    return __uint_as_float((unsigned)s << 16);
}

// ---------------- K0: fp32 -> bf16 convert + firstCross init ----------------
__global__ void __launch_bounds__(256) k0_convert(
    const float* __restrict__ x, const float* __restrict__ Win,
    unsigned short* __restrict__ xbf, unsigned short* __restrict__ wbf,
    unsigned* __restrict__ firstCross)
{
    const size_t NX = (size_t)M_ * I_;   // 8388608
    const size_t NW = (size_t)H_ * I_;   // 262144
    size_t tid = (size_t)blockIdx.x * 256 + threadIdx.x;
    size_t base = tid * 4;
    if (base < NX) {
        float4 v = *(const float4*)(x + base);
        ushort4 o;
        o.x = f2bf(v.x); o.y = f2bf(v.y); o.z = f2bf(v.z); o.w = f2bf(v.w);
        *(ushort4*)(xbf + base) = o;
    } else if (base < NX + NW) {
        size_t b2 = base - NX;
        float4 v = *(const float4*)(Win + b2);
        ushort4 o;
        o.x = f2bf(v.x); o.y = f2bf(v.y); o.z = f2bf(v.z); o.w = f2bf(v.w);
        *(ushort4*)(wbf + b2) = o;
    }
    if (blockIdx.x == 0 && threadIdx.x < 64) firstCross[threadIdx.x] = 0xFFFFFFFFu;
}

// ---- KF: fused ff-GEMM + speculative no-spike scan (ff never hits HBM) -----
// Block = (b, hn): 128 h columns x all 512 t, processed as 4 t-tiles of 128.
// GEMM inner loop identical to the verified K1; tile round-trips through LDS
// in [h][t] bf16 layout so 128 scan threads read bf16x8 vectors along t.
__global__ void __launch_bounds__(256) kf_gemm_scan(
    const unsigned short* __restrict__ xbf,   // [M_][I_]
    const unsigned short* __restrict__ wbf,   // [H_][I_]
    const float* __restrict__ b_in,
    const float* __restrict__ b_rec,
    const float* __restrict__ tau_m, const float* __restrict__ tau_n,
    unsigned* __restrict__ firstCross)
{
    __shared__ unsigned short lA[128 * 32];   // 8 KB
    __shared__ unsigned short lB[128 * 32];   // 8 KB
    __shared__ unsigned short lS[128 * LST];  // 34 KB, [h][t] bf16, stride LST

    const int tid  = threadIdx.x;
    const int w    = tid >> 6;
    const int lane = tid & 63;
    // XCD swizzle: all 8 h-tiles of batch b land on XCD b%8 -> x rows L2-local
    const int idx = blockIdx.x;
    const int b   = (idx & 7) | ((idx >> 6) << 3);
    const int hn  = (idx >> 3) & 7;
    const int wave_m = (w >> 1) * 64;   // t within tile
    const int wave_n = (w & 1) * 64;    // h within tile
    const int colrow = lane & 15;
    const int quad   = lane >> 4;

    // scan state (threads 0..127 each own one h column)
    float alpha = 0.f, beta = 0.f, br2 = 0.f, d = 0.f, mem = 0.f;
    unsigned cross = 0xFFFFFFFFu;
    if (tid < 128) {
        const int hs = hn * 128 + tid;
        alpha = 1.f / (1.f + expf(-tau_m[hs]));
        beta  = 1.f / (1.f + expf(-tau_n[hs]));
        br2   = b_in[hs] + b_rec[hs];   // bias folded into scan constant
    }

    const int rstage = lane >> 2;
    const int kcol   = (lane & 3) * 8;
    const unsigned short* gB0 = wbf + ((size_t)(hn * 128 + w * 32 + rstage)) * I_ + kcol;
    unsigned short* lA_w = lA + w * 1024;
    unsigned short* lB_w = lB + w * 1024;

    for (int tt = 0; tt < 4; ++tt) {
        const unsigned short* gA0 =
            xbf + ((size_t)(b * 512 + tt * 128 + w * 32 + rstage)) * I_ + kcol;

        f32x4 acc[4][4];
#pragma unroll
        for (int mi = 0; mi < 4; ++mi)
#pragma unroll
            for (int ni = 0; ni < 4; ++ni)
                acc[mi][ni] = (f32x4){0.f, 0.f, 0.f, 0.f};

        for (int kt = 0; kt < 8; ++kt) {
            const int k0 = kt * 32;
            __syncthreads();   // also fences prior tile's scan reads of lS
#pragma unroll
            for (int j = 0; j < 2; ++j) {
                __builtin_amdgcn_global_load_lds(
                    (const __attribute__((address_space(1))) void*)(gA0 + (size_t)j * 16 * I_ + k0),
                    (__attribute__((address_space(3))) void*)(lA_w + j * 512), 16, 0, 0);
                __builtin_amdgcn_global_load_lds(
                    (const __attribute__((address_space(1))) void*)(gB0 + (size_t)j * 16 * I_ + k0),
                    (__attribute__((address_space(3))) void*)(lB_w + j * 512), 16, 0, 0);
            }
            __syncthreads();

            bf16x8 af[4], bfr[4];
#pragma unroll
            for (int i = 0; i < 4; ++i) {
                af[i]  = *(const bf16x8*)&lA[(wave_m + i * 16 + colrow) * 32 + quad * 8];
                bfr[i] = *(const bf16x8*)&lB[(wave_n + i * 16 + colrow) * 32 + quad * 8];
            }
#pragma unroll
            for (int mi = 0; mi < 4; ++mi)
#pragma unroll
                for (int ni = 0; ni < 4; ++ni)
                    acc[mi][ni] = __builtin_amdgcn_mfma_f32_16x16x32_bf16(
                        af[mi], bfr[ni], acc[mi][ni], 0, 0, 0);
        }

        // dump tile to lS[h][t] as bf16; D layout: t = quad*4+r (+mi*16), h = colrow (+ni*16)
#pragma unroll
        for (int mi = 0; mi < 4; ++mi) {
            const int t0 = wave_m + mi * 16 + quad * 4;
#pragma unroll
            for (int ni = 0; ni < 4; ++ni) {
                const int h0 = wave_n + ni * 16 + colrow;
                u16x4 p;
                p[0] = f2bf(acc[mi][ni][0]);
                p[1] = f2bf(acc[mi][ni][1]);
                p[2] = f2bf(acc[mi][ni][2]);
                p[3] = f2bf(acc[mi][ni][3]);
                *(u16x4*)&lS[h0 * LST + t0] = p;   // 8B store, aligned
            }
        }
        __syncthreads();

        // scan 128 t-steps; threads 0..127 only (waves 2,3 wait at next barrier)
        if (tid < 128) {
            const unsigned short* row = lS + tid * LST;
            for (int tl0 = 0; tl0 < 128; tl0 += 16) {
                u16x8 v0 = *(const u16x8*)(row + tl0);
                u16x8 v1 = *(const u16x8*)(row + tl0 + 8);
                float f[16];
#pragma unroll
                for (int u = 0; u < 8; ++u) { f[u] = bf2f(v0[u]); f[8 + u] = bf2f(v1[u]); }
#pragma unroll
                for (int u = 0; u < 16; ++u) {
                    float tot = f[u] + br2;
                    d   = beta  * d   + (1.f - beta)  * tot;
                    mem = alpha * mem + (1.f - alpha) * d;
                    if (mem > 1.0f)
                        cross = min(cross, (unsigned)(tt * 128 + tl0 + u));
                }
            }
        }
    }
    if (tid < 128 && cross != 0xFFFFFFFFu) atomicMin(firstCross + b, cross);
}

// ------- K3: exact sequential repair, recomputes ff on the fly (runs ~never)
__global__ void __launch_bounds__(1024) k3_repair(
    const float* __restrict__ x, const float* __restrict__ W_in,
    const float* __restrict__ b_in,
    const float* __restrict__ W_rec, const float* __restrict__ b_rec,
    const float* __restrict__ tau_m, const float* __restrict__ tau_n,
    const unsigned* __restrict__ firstCross,
    unsigned long long* __restrict__ gmask)
{
    const int b = blockIdx.x;
    if (firstCross[b] == 0xFFFFFFFFu) return;   // block-uniform
    const int h = threadIdx.x;
    __shared__ float xrow[I_];
    __shared__ unsigned long long msk[16];
    if (h < 16) msk[h] = 0ull;
    const float alpha = 1.f / (1.f + expf(-tau_m[h]));
    const float beta  = 1.f / (1.f + expf(-tau_n[h]));
    const float bsum  = b_in[h] + b_rec[h];
    const float* wi = W_in + (size_t)h * I_;
    const float* wr = W_rec + (size_t)h * H_;
    float d = 0.f, mem = 0.f;
    for (int t = 0; t < S_; ++t) {
        __syncthreads();
        if (h < I_) xrow[h] = x[((size_t)b * S_ + t) * I_ + h];
        __syncthreads();
        float ffv = 0.f;
        for (int k = 0; k < I_; ++k) ffv += xrow[k] * wi[k];
        float rec = 0.f;
#pragma unroll
        for (int wd = 0; wd < 16; ++wd) {
            unsigned long long mw = msk[wd];
            while (mw) {
                int bit = __ffsll((long long)mw) - 1;
                rec += wr[(wd << 6) + bit];
                mw &= (mw - 1);
            }
        }
        float tot = ffv + bsum + rec;
        d   = beta  * d   + (1.f - beta)  * tot;
        mem = alpha * mem + (1.f - alpha) * d;
        int sp = (mem > 1.0f) ? 1 : 0;
        if (sp) mem = 0.f;
        unsigned long long bal = __ballot(sp);
        __syncthreads();   // all msk reads done before overwrite
        if ((h & 63) == 0) {
            msk[h >> 6] = bal;
            gmask[((size_t)b * S_ + t) * 16 + (h >> 6)] = bal;
        }
    }
}

// ---------------- K4: out = sigmoid(spike @ W_out^T + b_out) ----------------
__global__ void __launch_bounds__(256) k4_out(
    const float* __restrict__ W_out, const float* __restrict__ b_out,
    const unsigned* __restrict__ firstCross,
    const unsigned long long* __restrict__ gmask,
    float* __restrict__ out)
{
    const int idx = blockIdx.x * 256 + threadIdx.x;
    const int o  = idx & (O_ - 1);
    const int bt = idx >> 7;          // b*S_ + t
    const int b  = bt >> 9;
    const int t  = bt & (S_ - 1);
    float logit = b_out[o];
    if ((unsigned)t >= firstCross[b]) {
        const unsigned long long* m = gmask + (size_t)bt * 16;
        const float* wo = W_out + (size_t)o * H_;
#pragma unroll 4
        for (int w = 0; w < 16; ++w) {
            unsigned long long mw = m[w];
            while (mw) {
                int bit = __ffsll((long long)mw) - 1;
                logit += wo[(w << 6) + bit];
                mw &= (mw - 1);
            }
        }
    }
    out[idx] = 1.f / (1.f + expf(-logit));
}

extern "C" void kernel_launch(void* const* d_in, const int* in_sizes, int n_in,
                              void* d_out, int out_size, void* d_ws, size_t ws_size,
                              hipStream_t stream) {
    const float* x     = (const float*)d_in[0];
    const float* W_in  = (const float*)d_in[1];
    const float* b_in  = (const float*)d_in[2];
    const float* W_rec = (const float*)d_in[3];
    const float* b_rec = (const float*)d_in[4];
    const float* tau_m = (const float*)d_in[5];
    const float* tau_n = (const float*)d_in[6];
    const float* W_out = (const float*)d_in[7];
    const float* b_out = (const float*)d_in[8];
    float* out = (float*)d_out;

    char* ws = (char*)d_ws;
    size_t off = 0;
    unsigned short* xbf = (unsigned short*)(ws + off); off += (size_t)M_ * I_ * 2;   // 16 MB
    unsigned short* wbf = (unsigned short*)(ws + off); off += (size_t)H_ * I_ * 2;   // 0.5 MB
    unsigned long long* gmask = (unsigned long long*)(ws + off); off += (size_t)B_ * S_ * 16 * 8; // 4 MB
    unsigned* firstCross = (unsigned*)(ws + off);   off += 256;
    if (ws_size < off) return;  // workspace too small: fail visibly

    k0_convert<<<8448, 256, 0, stream>>>(x, W_in, xbf, wbf, firstCross);
    kf_gemm_scan<<<512, 256, 0, stream>>>(xbf, wbf, b_in, b_rec, tau_m, tau_n, firstCross);
    k3_repair<<<64, 1024, 0, stream>>>(x, W_in, b_in, W_rec, b_rec, tau_m, tau_n, firstCross, gmask);
    k4_out<<<16384, 256, 0, stream>>>(W_out, b_out, firstCross, gmask, out);
}

// Round 3
// 138.740 us; speedup vs baseline: 1.3387x; 1.0406x over previous
//
#include <hip/hip_runtime.h>
#include <hip/hip_bf16.h>
#include <stdint.h>

#define B_ 64
#define S_ 512
#define I_ 256
#define H_ 1024
#define O_ 128
#define M_ (B_*S_)   // 32768

typedef float f32x4 __attribute__((ext_vector_type(4)));
typedef unsigned short u16x4 __attribute__((ext_vector_type(4)));
typedef unsigned short u16x8 __attribute__((ext_vector_type(8)));

__device__ __forceinline__ unsigned short f2bf(float f) {
    unsigned u = __float_as_uint(f);
    u += 0x7FFFu + ((u >> 16) & 1u);
    return (unsigned short)(u >> 16);
}
__device__ __forceinline__ float bf2f(unsigned short s) {
    return __uint_as_float((unsigned)s << 16);
}

// ---- K0: fp32 -> fp8 e4m3, emitted in the swizzled [tile][kt][g][r][16B]
// layout that kf's global_load_lds staging consumes as a pure linear copy.
// Also inits firstCross / cnt (ws is re-poisoned 0xAA before every launch).
__global__ void __launch_bounds__(256) k0_convert(
    const float* __restrict__ x, const float* __restrict__ Win,
    uint8_t* __restrict__ xf8, uint8_t* __restrict__ wf8,
    unsigned* __restrict__ firstCross, unsigned* __restrict__ cnt)
{
    const unsigned tid = blockIdx.x * 256 + threadIdx.x;   // 540672 total
    const float* src;
    uint8_t* dst;
    if (tid < 524288u) {          // x: 256 tiles * 2 kt * 8 g * 128 r
        unsigned T = tid >> 11, rem = tid & 2047;
        unsigned kt = rem >> 10, g = (rem >> 7) & 7, r = rem & 127;
        src = x + ((size_t)(T * 128 + r)) * 256 + kt * 128 + g * 16;
        dst = xf8 + (size_t)tid * 16;
    } else {                      // W_in: 8 tiles * 2 kt * 8 g * 128 r
        unsigned t2 = tid - 524288u;
        unsigned T = t2 >> 11, rem = t2 & 2047;
        unsigned kt = rem >> 10, g = (rem >> 7) & 7, r = rem & 127;
        src = Win + ((size_t)(T * 128 + r)) * 256 + kt * 128 + g * 16;
        dst = wf8 + (size_t)t2 * 16;
    }
    const float4* s4 = (const float4*)src;
    float4 a = s4[0], b = s4[1], c = s4[2], e = s4[3];
    int w0 = 0, w1 = 0, w2 = 0, w3 = 0;
    w0 = __builtin_amdgcn_cvt_pk_fp8_f32(a.x, a.y, w0, false);
    w0 = __builtin_amdgcn_cvt_pk_fp8_f32(a.z, a.w, w0, true);
    w1 = __builtin_amdgcn_cvt_pk_fp8_f32(b.x, b.y, w1, false);
    w1 = __builtin_amdgcn_cvt_pk_fp8_f32(b.z, b.w, w1, true);
    w2 = __builtin_amdgcn_cvt_pk_fp8_f32(c.x, c.y, w2, false);
    w2 = __builtin_amdgcn_cvt_pk_fp8_f32(c.z, c.w, w2, true);
    w3 = __builtin_amdgcn_cvt_pk_fp8_f32(e.x, e.y, w3, false);
    w3 = __builtin_amdgcn_cvt_pk_fp8_f32(e.z, e.w, w3, true);
    int4 o; o.x = w0; o.y = w1; o.z = w2; o.w = w3;
    *(int4*)dst = o;
    if (blockIdx.x == 0) {
        if (threadIdx.x < 64) firstCross[threadIdx.x] = 0xFFFFFFFFu;
        else if (threadIdx.x < 128) cnt[threadIdx.x - 64] = 0u;
    }
}

// ---- KF: fused fp8 GEMM + speculative scan + (last block per b) output ----
// Block = (b, hn). 32 KB LDS total: lA/lB (16 KB each) overlaid with lS
// (disjoint lifetimes). BK=128 -> 2 staging rounds per t-tile, 64 MFMA each.
__global__ void __launch_bounds__(256) kf_gemm_scan(
    const uint8_t* __restrict__ xf8, const uint8_t* __restrict__ wf8,
    const float* __restrict__ b_in, const float* __restrict__ b_rec,
    const float* __restrict__ tau_m, const float* __restrict__ tau_n,
    const float* __restrict__ b_out,
    unsigned* __restrict__ firstCross, unsigned* __restrict__ cnt,
    float* __restrict__ out)
{
    __shared__ uint8_t lsbuf[32768];
    __shared__ int lastFlag;
    uint8_t* lA = lsbuf;
    uint8_t* lB = lsbuf + 16384;

    const int tid  = threadIdx.x;
    const int w    = tid >> 6;
    const int lane = tid & 63;
    const int idx  = blockIdx.x;
    const int b    = (idx & 7) | ((idx >> 6) << 3);   // XCD swizzle
    const int hn   = (idx >> 3) & 7;
    const int wave_m = (w >> 1) * 64;   // t
    const int wave_n = (w & 1) * 64;    // h
    const int colrow = lane & 15;
    const int quad   = lane >> 4;

    // scan state (threads 0..127 own one h column each)
    float alpha = 0.f, beta = 0.f, cbr = 0.f, oma = 0.f, ombr = 0.f;
    float d = 0.f, mem = 0.f;
    unsigned cross = 0xFFFFFFFFu;
    if (tid < 128) {
        const int hs = hn * 128 + tid;
        alpha = 1.f / (1.f + expf(-tau_m[hs]));
        beta  = 1.f / (1.f + expf(-tau_n[hs]));
        oma = 1.f - alpha; ombr = 1.f - beta;
        cbr = ombr * (b_in[hs] + b_rec[hs]);
    }

    const uint8_t* gB_tile = wf8 + (size_t)hn * 32768;

    for (int tt = 0; tt < 4; ++tt) {
        const uint8_t* gA_tile = xf8 + (size_t)(b * 4 + tt) * 32768;

        f32x4 acc[4][4];
#pragma unroll
        for (int mi = 0; mi < 4; ++mi)
#pragma unroll
            for (int ni = 0; ni < 4; ++ni)
                acc[mi][ni] = (f32x4){0.f, 0.f, 0.f, 0.f};

        for (int kt = 0; kt < 2; ++kt) {
            __syncthreads();  // prior lS-readers / prior-kt ds_reads done
            const int kofs = kt * 16384;
#pragma unroll
            for (int j = 0; j < 4; ++j) {
                const int chunk = ((j * 4 + w) << 10);
                __builtin_amdgcn_global_load_lds(
                    (const __attribute__((address_space(1))) void*)(gA_tile + kofs + chunk + lane * 16),
                    (__attribute__((address_space(3))) void*)(lA + chunk), 16, 0, 0);
                __builtin_amdgcn_global_load_lds(
                    (const __attribute__((address_space(1))) void*)(gB_tile + kofs + chunk + lane * 16),
                    (__attribute__((address_space(3))) void*)(lB + chunk), 16, 0, 0);
            }
            __syncthreads();  // DMA drained

#pragma unroll
            for (int kq = 0; kq < 4; ++kq) {
                const int fo = ((kq * 2 + (quad >> 1)) << 11) + ((quad & 1) << 3);
                long long af[4], bfr[4];
#pragma unroll
                for (int i = 0; i < 4; ++i) {
                    af[i]  = *(const long long*)(lA + fo + ((wave_m + i * 16 + colrow) << 4));
                    bfr[i] = *(const long long*)(lB + fo + ((wave_n + i * 16 + colrow) << 4));
                }
#pragma unroll
                for (int mi = 0; mi < 4; ++mi)
#pragma unroll
                    for (int ni = 0; ni < 4; ++ni)
                        acc[mi][ni] = __builtin_amdgcn_mfma_f32_16x16x32_fp8_fp8(
                            af[mi], bfr[ni], acc[mi][ni], 0, 0, 0);
            }
        }
        __syncthreads();   // all lA/lB ds_reads done before overlay as lS

        // dump tile -> lS[t-granule][h] bf16 (overlays lA/lB region)
#pragma unroll
        for (int mi = 0; mi < 4; ++mi) {
            const int t0 = wave_m + mi * 16 + quad * 4;
            const int gbase = (t0 >> 3) * 2048 + ((t0 & 4) << 1);
#pragma unroll
            for (int ni = 0; ni < 4; ++ni) {
                const int h0 = wave_n + ni * 16 + colrow;
                u16x4 p;
                p[0] = f2bf(acc[mi][ni][0]);
                p[1] = f2bf(acc[mi][ni][1]);
                p[2] = f2bf(acc[mi][ni][2]);
                p[3] = f2bf(acc[mi][ni][3]);
                *(u16x4*)(lsbuf + gbase + (h0 << 4)) = p;
            }
        }
        __syncthreads();

        if (tid < 128) {
            const uint8_t* rowp = lsbuf + tid * 16;
            for (int tl0 = 0; tl0 < 128; tl0 += 16) {
                const int gb = (tl0 >> 3) * 2048;
                u16x8 v0 = *(const u16x8*)(rowp + gb);
                u16x8 v1 = *(const u16x8*)(rowp + gb + 2048);
                float f[16];
#pragma unroll
                for (int u = 0; u < 8; ++u) { f[u] = bf2f(v0[u]); f[8 + u] = bf2f(v1[u]); }
#pragma unroll
                for (int u = 0; u < 16; ++u) {
                    d   = fmaf(beta,  d,   fmaf(ombr, f[u], cbr));
                    mem = fmaf(alpha, mem, oma * d);
                    if (mem > 1.0f) {
                        unsigned ts = (unsigned)(tt * 128 + tl0 + u);
                        if (ts < cross) cross = ts;
                    }
                }
            }
        }
    }

    if (tid < 128 && cross != 0xFFFFFFFFu) atomicMin(firstCross + b, cross);
    __syncthreads();
    if (tid == 0) {
        __threadfence();                       // publish atomicMins (release)
        unsigned old = atomicAdd(cnt + b, 1u);
        int flag = 0;
        if (old == 7u) {                       // last of the 8 blocks for b
            __threadfence();                   // acquire
            unsigned fc = atomicAdd(firstCross + b, 0u);  // device-scope read
            flag = (fc == 0xFFFFFFFFu) ? 1 : 0;
        }
        lastFlag = flag;
    }
    __syncthreads();
    if (lastFlag) {                            // block-uniform
        float* sg = (float*)lsbuf;             // lS region free now
        if (tid < 128) sg[tid] = 1.f / (1.f + expf(-b_out[tid]));
        __syncthreads();
        const int q = tid & 31;
        float4 v = *(float4*)(sg + q * 4);
        float* obase = out + (size_t)b * (S_ * O_) + q * 4;
        const int trow = tid >> 5;
#pragma unroll 4
        for (int k = 0; k < 64; ++k)
            *(float4*)(obase + (size_t)(trow + k * 8) * O_) = v;
    }
}

// ---- K3: exact repair + output for spiking batches (runs ~never) ----------
__global__ void __launch_bounds__(1024) k3_repair(
    const float* __restrict__ x, const float* __restrict__ W_in,
    const float* __restrict__ b_in,
    const float* __restrict__ W_rec, const float* __restrict__ b_rec,
    const float* __restrict__ tau_m, const float* __restrict__ tau_n,
    const float* __restrict__ W_out, const float* __restrict__ b_out,
    const unsigned* __restrict__ firstCross,
    unsigned long long* __restrict__ gmask,
    float* __restrict__ out)
{
    const int b = blockIdx.x;
    if (firstCross[b] == 0xFFFFFFFFu) return;   // block-uniform
    const int h = threadIdx.x;
    __shared__ float xrow[I_];
    __shared__ unsigned long long msk[16];
    if (h < 16) msk[h] = 0ull;
    const float alpha = 1.f / (1.f + expf(-tau_m[h]));
    const float beta  = 1.f / (1.f + expf(-tau_n[h]));
    const float bsum  = b_in[h] + b_rec[h];
    const float* wi = W_in + (size_t)h * I_;
    const float* wr = W_rec + (size_t)h * H_;
    float d = 0.f, mem = 0.f;
    for (int t = 0; t < S_; ++t) {
        __syncthreads();
        if (h < I_) xrow[h] = x[((size_t)b * S_ + t) * I_ + h];
        __syncthreads();
        float ffv = 0.f;
        for (int k = 0; k < I_; ++k) ffv += xrow[k] * wi[k];
        float rec = 0.f;
#pragma unroll
        for (int wd = 0; wd < 16; ++wd) {
            unsigned long long mw = msk[wd];
            while (mw) {
                int bit = __ffsll((long long)mw) - 1;
                rec += wr[(wd << 6) + bit];
                mw &= (mw - 1);
            }
        }
        float tot = ffv + bsum + rec;
        d   = beta  * d   + (1.f - beta)  * tot;
        mem = alpha * mem + (1.f - alpha) * d;
        int sp = (mem > 1.0f) ? 1 : 0;
        if (sp) mem = 0.f;
        unsigned long long bal = __ballot(sp);
        __syncthreads();
        if ((h & 63) == 0) {
            msk[h >> 6] = bal;
            gmask[((size_t)b * S_ + t) * 16 + (h >> 6)] = bal;
        }
    }
    __syncthreads();
    __threadfence_block();
    // phase 2: outputs for this batch (rare path, simplicity over speed)
    for (int i = h; i < S_ * O_; i += 1024) {
        const int t = i >> 7, o = i & (O_ - 1);
        float logit = b_out[o];
        const unsigned long long* m = gmask + ((size_t)b * S_ + t) * 16;
        const float* wo = W_out + (size_t)o * H_;
        for (int wd = 0; wd < 16; ++wd) {
            unsigned long long mw = m[wd];
            while (mw) {
                int bit = __ffsll((long long)mw) - 1;
                logit += wo[(wd << 6) + bit];
                mw &= (mw - 1);
            }
        }
        out[((size_t)b * S_ + t) * O_ + o] = 1.f / (1.f + expf(-logit));
    }
}

extern "C" void kernel_launch(void* const* d_in, const int* in_sizes, int n_in,
                              void* d_out, int out_size, void* d_ws, size_t ws_size,
                              hipStream_t stream) {
    const float* x     = (const float*)d_in[0];
    const float* W_in  = (const float*)d_in[1];
    const float* b_in  = (const float*)d_in[2];
    const float* W_rec = (const float*)d_in[3];
    const float* b_rec = (const float*)d_in[4];
    const float* tau_m = (const float*)d_in[5];
    const float* tau_n = (const float*)d_in[6];
    const float* W_out = (const float*)d_in[7];
    const float* b_out = (const float*)d_in[8];
    float* out = (float*)d_out;

    char* ws = (char*)d_ws;
    size_t off = 0;
    uint8_t* xf8 = (uint8_t*)(ws + off);               off += (size_t)M_ * I_;        // 8 MB
    uint8_t* wf8 = (uint8_t*)(ws + off);               off += (size_t)H_ * I_;        // 256 KB
    unsigned long long* gmask = (unsigned long long*)(ws + off); off += (size_t)B_ * S_ * 16 * 8; // 4 MB
    unsigned* firstCross = (unsigned*)(ws + off);      off += 256;
    unsigned* cnt = (unsigned*)(ws + off);             off += 256;
    if (ws_size < off) return;

    k0_convert<<<2112, 256, 0, stream>>>(x, W_in, xf8, wf8, firstCross, cnt);
    kf_gemm_scan<<<512, 256, 0, stream>>>(xf8, wf8, b_in, b_rec, tau_m, tau_n,
                                          b_out, firstCross, cnt, out);
    k3_repair<<<64, 1024, 0, stream>>>(x, W_in, b_in, W_rec, b_rec, tau_m, tau_n,
                                       W_out, b_out, firstCross, gmask, out);
}